// Round 12
// baseline (415.392 us; speedup 1.0000x reference)
//
#include <hip/hip_runtime.h>
#include <hip/hip_fp16.h>

#define NT 256
#define NPB 256        // nodes per bucket (dst >> 8)
#define MAXBUK 512
#define A3_TILE 4096
#define NSTRIP 16
#define STRIP_SH 13
#define CAP 12288      // per-bucket capacity (mean 8184, +10 sigma ~9.1K)

typedef _Float16 half8 __attribute__((ext_vector_type(8)));
typedef float floatx4 __attribute__((ext_vector_type(4)));

// ---------------- bucketed CSR build (fixed-capacity, validated r11) ----------------

__global__ void init_bcur(int* __restrict__ bcur, int nbuk) {
    int b = blockIdx.x * blockDim.x + threadIdx.x;
    if (b < nbuk) bcur[b] = b * CAP;
}

__global__ __launch_bounds__(256) void partition(const int* __restrict__ ei, int E,
                                                 int* __restrict__ bcur,
                                                 unsigned int* __restrict__ pairs) {
    __shared__ int h[MAXBUK];
    __shared__ int base[MAXBUK];
    int t = threadIdx.x;
    for (int i = t; i < MAXBUK; i += 256) h[i] = 0;
    __syncthreads();
    int e0 = blockIdx.x * A3_TILE + t * 16;
    int src[16], dst[16];
    if (((E & 3) == 0) && (e0 + 15 < E)) {
        const int4* p4s = (const int4*)(ei + e0);
        const int4* p4d = (const int4*)(ei + E + e0);
#pragma unroll
        for (int j4 = 0; j4 < 4; j4++) {
            int4 s4 = p4s[j4];
            int4 d4 = p4d[j4];
            src[j4 * 4 + 0] = s4.x; dst[j4 * 4 + 0] = d4.x;
            src[j4 * 4 + 1] = s4.y; dst[j4 * 4 + 1] = d4.y;
            src[j4 * 4 + 2] = s4.z; dst[j4 * 4 + 2] = d4.z;
            src[j4 * 4 + 3] = s4.w; dst[j4 * 4 + 3] = d4.w;
        }
    } else {
#pragma unroll
        for (int j = 0; j < 16; j++) {
            int e = e0 + j;
            if (e < E) {
                src[j] = ei[e];
                dst[j] = ei[E + e];
            } else {
                dst[j] = -1;
            }
        }
    }
#pragma unroll
    for (int j = 0; j < 16; j++)
        if (dst[j] >= 0) atomicAdd(&h[dst[j] >> 8], 1);
    __syncthreads();
    for (int b = t; b < MAXBUK; b += 256) {
        int c = h[b];
        base[b] = c ? atomicAdd(&bcur[b], c) : 0;
        h[b] = 0;
    }
    __syncthreads();
#pragma unroll
    for (int j = 0; j < 16; j++) {
        if (dst[j] >= 0) {
            int bkt = dst[j] >> 8;
            int r = atomicAdd(&h[bkt], 1);
            pairs[base[bkt] + r] = ((unsigned)(dst[j] & (NPB - 1)) << 24) | (unsigned)src[j];
        }
    }
}

__global__ __launch_bounds__(512) void build_bucket(const unsigned int* __restrict__ pairs,
                                                    const int* __restrict__ bcur,
                                                    int* __restrict__ csr_off,
                                                    int* __restrict__ csr_end,
                                                    int* __restrict__ csr_src,
                                                    float* __restrict__ invd, int N) {
    __shared__ int h2[NPB * NSTRIP];
    __shared__ int tsum[512];
    int b = blockIdx.x, t = threadIdx.x;
    int gb0 = b * CAP;
    int cnt = bcur[b] - gb0;
    int gb1 = gb0 + cnt;
    int nb0 = b << 8;
    int nn = min(NPB, N - nb0);
    for (int i = t; i < NPB * NSTRIP; i += 512) h2[i] = 0;
    __syncthreads();
    for (int i = gb0 + t; i < gb1; i += 512) {
        unsigned p = pairs[i];
        int ld = p >> 24;
        int st = (int)((p & 0xFFFFFFu) >> STRIP_SH);
        atomicAdd(&h2[ld * NSTRIP + st], 1);
    }
    __syncthreads();
    if (t < nn) {
        int d = 0;
#pragma unroll
        for (int ss = 0; ss < NSTRIP; ss++) d += h2[t * NSTRIP + ss];
        invd[nb0 + t] = 1.0f / (float)max(d, 1);
    }
    int v[8];
    int loc = 0;
#pragma unroll
    for (int j = 0; j < 8; j++) {
        v[j] = h2[t * 8 + j];
        loc += v[j];
    }
    tsum[t] = loc;
    __syncthreads();
    for (int off = 1; off < 512; off <<= 1) {
        int xv = 0;
        if (t >= off) xv = tsum[t - off];
        __syncthreads();
        tsum[t] += xv;
        __syncthreads();
    }
    int run = (t == 0) ? 0 : tsum[t - 1];
#pragma unroll
    for (int j = 0; j < 8; j++) {
        h2[t * 8 + j] = run;
        run += v[j];
    }
    __syncthreads();
    if (t < nn) {
        csr_off[nb0 + t] = gb0 + h2[t * NSTRIP];
        int endv = (t == NPB - 1) ? cnt : h2[(t + 1) * NSTRIP];
        csr_end[nb0 + t] = gb0 + endv;
    }
    __syncthreads();
    for (int i = gb0 + t; i < gb1; i += 512) {
        unsigned p = pairs[i];
        int ld = p >> 24;
        unsigned srcv = p & 0xFFFFFFu;
        int st = (int)(srcv >> STRIP_SH);
        int pos = atomicAdd(&h2[ld * NSTRIP + st], 1);
        csr_src[gb0 + pos] = (int)srcv;
    }
}

// ---------------- feature pipeline ----------------
// xroot0: [N][16] fp16. xroot1/2: 4 planes of [N][16] fp16 (plane p at offset p*N*16).
// act k-layout: k=0..63 mean (k = plane*16+ch), k=64..127 root (64 + plane*16+ch)
// -> identical to natural channel order, so wt layout is unchanged.

__device__ inline void acc4v(float* acc, uint2 hv) {
    const __half2* hp = reinterpret_cast<const __half2*>(&hv);
#pragma unroll
    for (int j = 0; j < 2; j++) {
        float2 f = __half22float2(hp[j]);
        acc[2 * j] += f.x;
        acc[2 * j + 1] += f.y;
    }
}

__global__ void pad_x(const float* __restrict__ x, __half* __restrict__ xroot0, int N) {
    int i = blockIdx.x * blockDim.x + threadIdx.x;
    if (i < N * 16) {
        int n = i >> 4, c = i & 15;
        float v = (c < 13) ? x[n * 13 + c] : 0.f;
        xroot0[i] = __float2half(v);
    }
}

// fused layer 0: agg(16ch) -> LDS -> K=32 MFMA -> plane-formatted xroot1
__global__ __launch_bounds__(512) void fused0(
    const __half* __restrict__ xroot0, const int* __restrict__ off, const int* __restrict__ end,
    const int* __restrict__ csr, const float* __restrict__ invd,
    const float* __restrict__ Wl, const float* __restrict__ bl, const float* __restrict__ Wr,
    __half* __restrict__ xn, int N) {
    __shared__ _Float16 act[64 * 40];
    __shared__ _Float16 wt[64 * 40];
    __shared__ float bs[64];
    int t = threadIdx.x;
    for (int i = t; i < 2048; i += 512) {
        int k = i >> 6, c = i & 63;
        float v;
        if (k < 16) v = (k < 13) ? Wl[k * 64 + c] : 0.f;
        else {
            int kk = k - 16;
            v = (kk < 13) ? Wr[kk * 64 + c] : 0.f;
        }
        wt[c * 40 + k] = (_Float16)v;
    }
    if (t < 64) bs[t] = bl[t];
    int n0 = blockIdx.x * 64;
    if (t < 256) {
        int node = t >> 2, cc4 = (t & 3) * 4;
        int n = min(n0 + node, N - 1);
        uint2 rv = *(const uint2*)(xroot0 + (size_t)n * 16 + cc4);
        *(uint2*)&act[node * 40 + 16 + cc4] = rv;
    }
    int lane = t & 63, wid = t >> 6;
    int g = lane >> 2, c4 = (lane & 3) * 4;
#pragma unroll 1
    for (int rr = 0; rr < 8; rr++) {
        int nloc = rr * 8 + wid;
        int n = min(n0 + nloc, N - 1);
        float sc = invd[n];
        int e0 = off[n], e1 = end[n];
        float acc[4] = {0, 0, 0, 0};
        int e = e0;
        for (; e + 31 < e1; e += 32) {
            int s0 = csr[e + g];
            int s1 = csr[e + 16 + g];
            uint2 h0 = *(const uint2*)(xroot0 + (size_t)s0 * 16 + c4);
            uint2 h1 = *(const uint2*)(xroot0 + (size_t)s1 * 16 + c4);
            acc4v(acc, h0);
            acc4v(acc, h1);
        }
        if (e + 15 < e1) {
            uint2 h0 = *(const uint2*)(xroot0 + (size_t)csr[e + g] * 16 + c4);
            acc4v(acc, h0);
            e += 16;
        }
        if (e + g < e1) {
            uint2 h0 = *(const uint2*)(xroot0 + (size_t)csr[e + g] * 16 + c4);
            acc4v(acc, h0);
        }
#pragma unroll
        for (int o = 4; o <= 32; o <<= 1) {
#pragma unroll
            for (int j = 0; j < 4; j++) acc[j] += __shfl_xor(acc[j], o);
        }
        if (lane < 4) {
            __half2 p[2];
            p[0] = __floats2half2_rn(acc[0] * sc, acc[1] * sc);
            p[1] = __floats2half2_rn(acc[2] * sc, acc[3] * sc);
            *(uint2*)&act[nloc * 40 + lane * 4] = *(const uint2*)p;
        }
    }
    __syncthreads();
    if (wid < 4) {
        size_t N16 = (size_t)N * 16;
        int row = lane & 15, kg = lane >> 4;
        half8 a = *(const half8*)&act[(wid * 16 + row) * 40 + kg * 8];
        floatx4 ac[4];
#pragma unroll
        for (int tt = 0; tt < 4; tt++) ac[tt] = (floatx4){0.f, 0.f, 0.f, 0.f};
#pragma unroll
        for (int tt = 0; tt < 4; tt++) {
            half8 b = *(const half8*)&wt[(tt * 16 + row) * 40 + kg * 8];
            ac[tt] = __builtin_amdgcn_mfma_f32_16x16x32_f16(a, b, ac[tt], 0, 0, 0);
        }
#pragma unroll
        for (int tt = 0; tt < 4; tt++) {
            float bias = bs[tt * 16 + row];
#pragma unroll
            for (int r = 0; r < 4; r++) {
                int n = n0 + wid * 16 + kg * 4 + r;
                if (n < N)
                    xn[(size_t)tt * N16 + (size_t)n * 16 + row] =
                        __float2half(fmaxf(ac[tt][r] + bias, 0.f));
            }
        }
    }
}

// fused layers 1/2 v2: plane-split gather (4 x 3.2MB L2-resident planes),
// lane-quad per node (no shuffle reduce), 128-node tiles, 8-wave MFMA.
// LAST=1 fuses layer-3 projection -> s3,r3.
template <int LAST>
__global__ __launch_bounds__(512) void fused_layer(
    const __half* __restrict__ xr, const int* __restrict__ off, const int* __restrict__ end,
    const int* __restrict__ csr, const float* __restrict__ invd,
    const float* __restrict__ Wl, const float* __restrict__ bl, const float* __restrict__ Wr,
    __half* __restrict__ xn,
    const float* __restrict__ Wl3, const float* __restrict__ bl3, const float* __restrict__ Wr3,
    float* __restrict__ s3, float* __restrict__ r3, int N) {
    __shared__ _Float16 act[128 * 136];
    __shared__ _Float16 wt[64 * 136];
    __shared__ float bs[64];
    int t = threadIdx.x;
    for (int i = t; i < 8192; i += 512) {
        int k = i >> 6, c = i & 63;
        float v = (k < 64) ? Wl[k * 64 + c] : Wr[(k - 64) * 64 + c];
        wt[c * 136 + k] = (_Float16)v;
    }
    if (t < 64) bs[t] = bl[t];

    int n0 = blockIdx.x * 128;
    int lane = t & 63, wid = t >> 6;
    int nloc = wid * 16 + (lane >> 2);  // node 0..127 (quad per node)
    int c4 = (lane & 3) * 4;            // 4 channels within plane (lane-exclusive)
    int n = min(n0 + nloc, N - 1);
    int e0 = off[n], e1 = end[n];
    float sc = invd[n];
    size_t N16 = (size_t)N * 16;
    int rnode = t >> 2;                 // root-slice node 0..127
    int rn = min(n0 + rnode, N - 1);
    int rc4 = (t & 3) * 4;

#pragma unroll 1
    for (int p = 0; p < 4; p++) {
        const __half* plane = xr + (size_t)p * N16;
        // root slice for this plane (reads the currently-hot plane)
        {
            uint2 rv = *(const uint2*)(plane + (size_t)rn * 16 + rc4);
            *(uint2*)&act[rnode * 136 + 64 + p * 16 + rc4] = rv;
        }
        // gather: serial edge walk, quad covers the 32 B row
        float acc[4] = {0, 0, 0, 0};
        int e = e0;
        for (; e + 3 < e1; e += 4) {
            int s0 = csr[e], s1 = csr[e + 1], s2 = csr[e + 2], s3v = csr[e + 3];
            uint2 h0 = *(const uint2*)(plane + (size_t)s0 * 16 + c4);
            uint2 h1 = *(const uint2*)(plane + (size_t)s1 * 16 + c4);
            uint2 h2 = *(const uint2*)(plane + (size_t)s2 * 16 + c4);
            uint2 h3 = *(const uint2*)(plane + (size_t)s3v * 16 + c4);
            acc4v(acc, h0);
            acc4v(acc, h1);
            acc4v(acc, h2);
            acc4v(acc, h3);
        }
        for (; e < e1; e++) {
            uint2 h0 = *(const uint2*)(plane + (size_t)csr[e] * 16 + c4);
            acc4v(acc, h0);
        }
        __half2 pk[2];
        pk[0] = __floats2half2_rn(acc[0] * sc, acc[1] * sc);
        pk[1] = __floats2half2_rn(acc[2] * sc, acc[3] * sc);
        *(uint2*)&act[nloc * 136 + p * 16 + c4] = *(const uint2*)pk;
    }
    __syncthreads();

    // MFMA: 8 waves x 16 rows (M=128)
    {
        int row = lane & 15, kg = lane >> 4;
        const _Float16* abase = &act[(wid * 16 + row) * 136 + kg * 8];
        half8 a[4];
#pragma unroll
        for (int kk = 0; kk < 4; kk++) a[kk] = *(const half8*)(abase + kk * 32);
        floatx4 ac[4];
#pragma unroll
        for (int tt = 0; tt < 4; tt++) ac[tt] = (floatx4){0.f, 0.f, 0.f, 0.f};
#pragma unroll
        for (int kk = 0; kk < 4; kk++) {
#pragma unroll
            for (int tt = 0; tt < 4; tt++) {
                half8 b = *(const half8*)&wt[(tt * 16 + row) * 136 + kk * 32 + kg * 8];
                ac[tt] = __builtin_amdgcn_mfma_f32_16x16x32_f16(a[kk], b, ac[tt], 0, 0, 0);
            }
        }
        if (LAST == 0) {
#pragma unroll
            for (int tt = 0; tt < 4; tt++) {
                float bias = bs[tt * 16 + row];
#pragma unroll
                for (int r = 0; r < 4; r++) {
                    int nw = n0 + wid * 16 + kg * 4 + r;
                    if (nw < N)
                        xn[(size_t)tt * N16 + (size_t)nw * 16 + row] =
                            __float2half(fmaxf(ac[tt][r] + bias, 0.f));
                }
            }
        } else {
            float wl3v[4], wr3v[4];
#pragma unroll
            for (int tt = 0; tt < 4; tt++) {
                int col = tt * 16 + row;
                wl3v[tt] = Wl3[col];
                wr3v[tt] = Wr3[col];
            }
            float b3 = bl3[0];
            float sp[4], rp[4];
#pragma unroll
            for (int r = 0; r < 4; r++) {
                float spv = 0.f, rpv = 0.f;
#pragma unroll
                for (int tt = 0; tt < 4; tt++) {
                    float v = fmaxf(ac[tt][r] + bs[tt * 16 + row], 0.f);
                    spv += v * wl3v[tt];
                    rpv += v * wr3v[tt];
                }
                sp[r] = spv;
                rp[r] = rpv;
            }
#pragma unroll
            for (int o = 1; o <= 8; o <<= 1) {
#pragma unroll
                for (int r = 0; r < 4; r++) {
                    sp[r] += __shfl_xor(sp[r], o);
                    rp[r] += __shfl_xor(rp[r], o);
                }
            }
            if (row == 0) {
#pragma unroll
                for (int r = 0; r < 4; r++) {
                    int nw = n0 + wid * 16 + kg * 4 + r;
                    if (nw < N) {
                        s3[nw] = sp[r];
                        r3[nw] = rp[r] + b3;
                    }
                }
            }
        }
    }
}

__global__ void sage_last_scalar(
    const float* __restrict__ s3, const float* __restrict__ r3, const int* __restrict__ off,
    const int* __restrict__ end, const int* __restrict__ csr, const float* __restrict__ invd,
    float* __restrict__ out, int N) {
    int n = blockIdx.x * blockDim.x + threadIdx.x;
    if (n >= N) return;
    int e0 = off[n], e1 = end[n];
    float acc = 0.f;
    int e = e0;
    for (; e + 3 < e1; e += 4) {
        float a0 = s3[csr[e]], a1 = s3[csr[e + 1]], a2 = s3[csr[e + 2]], a3 = s3[csr[e + 3]];
        acc += a0 + a1 + a2 + a3;
    }
    for (; e < e1; e++) acc += s3[csr[e]];
    out[n] = acc * invd[n] + r3[n];
}

// ---------------- launch ----------------

extern "C" void kernel_launch(void* const* d_in, const int* in_sizes, int n_in,
                              void* d_out, int out_size, void* d_ws, size_t ws_size,
                              hipStream_t stream) {
    const float* x0 = (const float*)d_in[0];
    const int* ei = (const int*)d_in[1];
    const float* Wl[4] = {(const float*)d_in[2], (const float*)d_in[5], (const float*)d_in[8],
                          (const float*)d_in[11]};
    const float* bl[4] = {(const float*)d_in[3], (const float*)d_in[6], (const float*)d_in[9],
                          (const float*)d_in[12]};
    const float* Wr[4] = {(const float*)d_in[4], (const float*)d_in[7], (const float*)d_in[10],
                          (const float*)d_in[13]};
    float* out = (float*)d_out;

    const int N = in_sizes[0] / 13;
    const int E = in_sizes[1] / 2;
    const int nbuk = (N + NPB - 1) / NPB;

    char* w = (char*)d_ws;
    auto carve = [&](size_t bytes) {
        void* p = (void*)w;
        w += (bytes + 255) & ~size_t(255);
        return p;
    };
    int* bcur = (int*)carve((size_t)MAXBUK * 4);
    unsigned int* pairs = (unsigned int*)carve((size_t)nbuk * CAP * 4);
    int* csr_off = (int*)carve((size_t)N * 4);
    int* csr_end = (int*)carve((size_t)N * 4);
    int* csr_src = (int*)carve((size_t)nbuk * CAP * 4);
    float* invd = (float*)carve((size_t)N * 4);
    __half* xroot0 = (__half*)carve((size_t)N * 16 * 2);
    __half* xroot1 = (__half*)carve((size_t)N * 64 * 2);  // 4 planes [N][16]
    __half* xroot2 = (__half*)carve((size_t)N * 64 * 2);  // 4 planes [N][16]
    float* s3 = (float*)carve((size_t)N * 4);
    float* r3 = (float*)carve((size_t)N * 4);

    init_bcur<<<(nbuk + 255) / 256, 256, 0, stream>>>(bcur, nbuk);
    partition<<<(E + A3_TILE - 1) / A3_TILE, 256, 0, stream>>>(ei, E, bcur, pairs);
    build_bucket<<<nbuk, 512, 0, stream>>>(pairs, bcur, csr_off, csr_end, csr_src, invd, N);

    pad_x<<<(N * 16 + NT - 1) / NT, NT, 0, stream>>>(x0, xroot0, N);

    int gblk0 = (N + 63) / 64;
    int gblk = (N + 127) / 128;
    fused0<<<gblk0, 512, 0, stream>>>(xroot0, csr_off, csr_end, csr_src, invd,
                                      Wl[0], bl[0], Wr[0], xroot1, N);
    fused_layer<0><<<gblk, 512, 0, stream>>>(xroot1, csr_off, csr_end, csr_src, invd,
                                             Wl[1], bl[1], Wr[1], xroot2,
                                             nullptr, nullptr, nullptr, nullptr, nullptr, N);
    fused_layer<1><<<gblk, 512, 0, stream>>>(xroot2, csr_off, csr_end, csr_src, invd,
                                             Wl[2], bl[2], Wr[2], nullptr,
                                             Wl[3], bl[3], Wr[3], s3, r3, N);
    sage_last_scalar<<<(N + NT - 1) / NT, NT, 0, stream>>>(s3, r3, csr_off, csr_end, csr_src,
                                                           invd, out, N);
}

// Round 13
// 240.028 us; speedup vs baseline: 1.7306x; 1.7306x over previous
//
#include <hip/hip_runtime.h>
#include <hip/hip_fp16.h>

#define NT 256
#define NPB 256        // nodes per bucket (dst >> 8)
#define MAXBUK 512
#define A3_TILE 8192   // 256 thr x 32 edges (r12->r13: was 4096; longer write runs)
#define NSTRIP 16
#define STRIP_SH 13
#define CAP 12288      // per-bucket capacity (mean 8184, +10 sigma ~9.1K)

typedef _Float16 half8 __attribute__((ext_vector_type(8)));
typedef float floatx4 __attribute__((ext_vector_type(4)));

// ---------------- bucketed CSR build (fixed-capacity, validated r11) ----------------

__global__ void init_bcur(int* __restrict__ bcur, int nbuk) {
    int b = blockIdx.x * blockDim.x + threadIdx.x;
    if (b < nbuk) bcur[b] = b * CAP;
}

__global__ __launch_bounds__(256) void partition(const int* __restrict__ ei, int E,
                                                 int* __restrict__ bcur,
                                                 unsigned int* __restrict__ pairs) {
    __shared__ int h[MAXBUK];
    __shared__ int base[MAXBUK];
    int t = threadIdx.x;
    for (int i = t; i < MAXBUK; i += 256) h[i] = 0;
    __syncthreads();
    int e0 = blockIdx.x * A3_TILE + t * 32;
    int src[32], dst[32];
    if (((E & 3) == 0) && (e0 + 31 < E)) {
        const int4* p4s = (const int4*)(ei + e0);
        const int4* p4d = (const int4*)(ei + E + e0);
#pragma unroll
        for (int j4 = 0; j4 < 8; j4++) {
            int4 s4 = p4s[j4];
            int4 d4 = p4d[j4];
            src[j4 * 4 + 0] = s4.x; dst[j4 * 4 + 0] = d4.x;
            src[j4 * 4 + 1] = s4.y; dst[j4 * 4 + 1] = d4.y;
            src[j4 * 4 + 2] = s4.z; dst[j4 * 4 + 2] = d4.z;
            src[j4 * 4 + 3] = s4.w; dst[j4 * 4 + 3] = d4.w;
        }
    } else {
#pragma unroll
        for (int j = 0; j < 32; j++) {
            int e = e0 + j;
            if (e < E) {
                src[j] = ei[e];
                dst[j] = ei[E + e];
            } else {
                dst[j] = -1;
            }
        }
    }
#pragma unroll
    for (int j = 0; j < 32; j++)
        if (dst[j] >= 0) atomicAdd(&h[dst[j] >> 8], 1);
    __syncthreads();
    for (int b = t; b < MAXBUK; b += 256) {
        int c = h[b];
        base[b] = c ? atomicAdd(&bcur[b], c) : 0;
        h[b] = 0;
    }
    __syncthreads();
#pragma unroll
    for (int j = 0; j < 32; j++) {
        if (dst[j] >= 0) {
            int bkt = dst[j] >> 8;
            int r = atomicAdd(&h[bkt], 1);
            pairs[base[bkt] + r] = ((unsigned)(dst[j] & (NPB - 1)) << 24) | (unsigned)src[j];
        }
    }
}

__global__ __launch_bounds__(512) void build_bucket(const unsigned int* __restrict__ pairs,
                                                    const int* __restrict__ bcur,
                                                    int* __restrict__ csr_off,
                                                    int* __restrict__ csr_end,
                                                    int* __restrict__ csr_src,
                                                    float* __restrict__ invd, int N) {
    __shared__ int h2[NPB * NSTRIP];
    __shared__ int tsum[512];
    int b = blockIdx.x, t = threadIdx.x;
    int gb0 = b * CAP;
    int cnt = bcur[b] - gb0;
    int gb1 = gb0 + cnt;
    int nb0 = b << 8;
    int nn = min(NPB, N - nb0);
    for (int i = t; i < NPB * NSTRIP; i += 512) h2[i] = 0;
    __syncthreads();
    for (int i = gb0 + t; i < gb1; i += 512) {
        unsigned p = pairs[i];
        int ld = p >> 24;
        int st = (int)((p & 0xFFFFFFu) >> STRIP_SH);
        atomicAdd(&h2[ld * NSTRIP + st], 1);
    }
    __syncthreads();
    if (t < nn) {
        int d = 0;
#pragma unroll
        for (int ss = 0; ss < NSTRIP; ss++) d += h2[t * NSTRIP + ss];
        invd[nb0 + t] = 1.0f / (float)max(d, 1);
    }
    int v[8];
    int loc = 0;
#pragma unroll
    for (int j = 0; j < 8; j++) {
        v[j] = h2[t * 8 + j];
        loc += v[j];
    }
    tsum[t] = loc;
    __syncthreads();
    for (int off = 1; off < 512; off <<= 1) {
        int xv = 0;
        if (t >= off) xv = tsum[t - off];
        __syncthreads();
        tsum[t] += xv;
        __syncthreads();
    }
    int run = (t == 0) ? 0 : tsum[t - 1];
#pragma unroll
    for (int j = 0; j < 8; j++) {
        h2[t * 8 + j] = run;
        run += v[j];
    }
    __syncthreads();
    if (t < nn) {
        csr_off[nb0 + t] = gb0 + h2[t * NSTRIP];
        int endv = (t == NPB - 1) ? cnt : h2[(t + 1) * NSTRIP];
        csr_end[nb0 + t] = gb0 + endv;
    }
    __syncthreads();
    for (int i = gb0 + t; i < gb1; i += 512) {
        unsigned p = pairs[i];
        int ld = p >> 24;
        unsigned srcv = p & 0xFFFFFFu;
        int st = (int)(srcv >> STRIP_SH);
        int pos = atomicAdd(&h2[ld * NSTRIP + st], 1);
        csr_src[gb0 + pos] = (int)srcv;
    }
}

// ---------------- feature pipeline ----------------
// xroot0: [N][16] fp16. xroot1/2: [N][64] fp16.

__device__ inline void acc8(float* acc, uint4 hv) {
    const __half2* hp = reinterpret_cast<const __half2*>(&hv);
#pragma unroll
    for (int j = 0; j < 4; j++) {
        float2 f = __half22float2(hp[j]);
        acc[2 * j] += f.x;
        acc[2 * j + 1] += f.y;
    }
}

__device__ inline void acc4v(float* acc, uint2 hv) {
    const __half2* hp = reinterpret_cast<const __half2*>(&hv);
#pragma unroll
    for (int j = 0; j < 2; j++) {
        float2 f = __half22float2(hp[j]);
        acc[2 * j] += f.x;
        acc[2 * j + 1] += f.y;
    }
}

__global__ void pad_x(const float* __restrict__ x, __half* __restrict__ xroot0, int N) {
    int i = blockIdx.x * blockDim.x + threadIdx.x;
    if (i < N * 16) {
        int n = i >> 4, c = i & 15;
        float v = (c < 13) ? x[n * 13 + c] : 0.f;
        xroot0[i] = __float2half(v);
    }
}

// fused layer 0: agg(16ch) -> LDS -> K=32 MFMA -> xroot1
__global__ __launch_bounds__(512) void fused0(
    const __half* __restrict__ xroot0, const int* __restrict__ off, const int* __restrict__ end,
    const int* __restrict__ csr, const float* __restrict__ invd,
    const float* __restrict__ Wl, const float* __restrict__ bl, const float* __restrict__ Wr,
    __half* __restrict__ xroot1, int N) {
    __shared__ _Float16 act[64 * 40];
    __shared__ _Float16 wt[64 * 40];
    __shared__ float bs[64];
    int t = threadIdx.x;
    for (int i = t; i < 2048; i += 512) {
        int k = i >> 6, c = i & 63;
        float v;
        if (k < 16) v = (k < 13) ? Wl[k * 64 + c] : 0.f;
        else {
            int kk = k - 16;
            v = (kk < 13) ? Wr[kk * 64 + c] : 0.f;
        }
        wt[c * 40 + k] = (_Float16)v;
    }
    if (t < 64) bs[t] = bl[t];
    int n0 = blockIdx.x * 64;
    if (t < 256) {
        int node = t >> 2, cc4 = (t & 3) * 4;
        int n = min(n0 + node, N - 1);
        uint2 rv = *(const uint2*)(xroot0 + (size_t)n * 16 + cc4);
        *(uint2*)&act[node * 40 + 16 + cc4] = rv;
    }
    int lane = t & 63, wid = t >> 6;
    int g = lane >> 2, c4 = (lane & 3) * 4;
#pragma unroll 1
    for (int rr = 0; rr < 8; rr++) {
        int nloc = rr * 8 + wid;
        int n = min(n0 + nloc, N - 1);
        float sc = invd[n];
        int e0 = off[n], e1 = end[n];
        float acc[4] = {0, 0, 0, 0};
        int e = e0;
        for (; e + 31 < e1; e += 32) {
            int s0 = csr[e + g];
            int s1 = csr[e + 16 + g];
            uint2 h0 = *(const uint2*)(xroot0 + (size_t)s0 * 16 + c4);
            uint2 h1 = *(const uint2*)(xroot0 + (size_t)s1 * 16 + c4);
            acc4v(acc, h0);
            acc4v(acc, h1);
        }
        if (e + 15 < e1) {
            uint2 h0 = *(const uint2*)(xroot0 + (size_t)csr[e + g] * 16 + c4);
            acc4v(acc, h0);
            e += 16;
        }
        if (e + g < e1) {
            uint2 h0 = *(const uint2*)(xroot0 + (size_t)csr[e + g] * 16 + c4);
            acc4v(acc, h0);
        }
#pragma unroll
        for (int o = 4; o <= 32; o <<= 1) {
#pragma unroll
            for (int j = 0; j < 4; j++) acc[j] += __shfl_xor(acc[j], o);
        }
        if (lane < 4) {
            __half2 p[2];
            p[0] = __floats2half2_rn(acc[0] * sc, acc[1] * sc);
            p[1] = __floats2half2_rn(acc[2] * sc, acc[3] * sc);
            *(uint2*)&act[nloc * 40 + lane * 4] = *(const uint2*)p;
        }
    }
    __syncthreads();
    if (wid < 4) {
        int row = lane & 15, kg = lane >> 4;
        half8 a = *(const half8*)&act[(wid * 16 + row) * 40 + kg * 8];
        floatx4 ac[4];
#pragma unroll
        for (int tt = 0; tt < 4; tt++) ac[tt] = (floatx4){0.f, 0.f, 0.f, 0.f};
#pragma unroll
        for (int tt = 0; tt < 4; tt++) {
            half8 b = *(const half8*)&wt[(tt * 16 + row) * 40 + kg * 8];
            ac[tt] = __builtin_amdgcn_mfma_f32_16x16x32_f16(a, b, ac[tt], 0, 0, 0);
        }
#pragma unroll
        for (int tt = 0; tt < 4; tt++) {
            int col = tt * 16 + row;
            float bias = bs[col];
#pragma unroll
            for (int r = 0; r < 4; r++) {
                int n = n0 + wid * 16 + kg * 4 + r;
                if (n < N)
                    xroot1[(size_t)n * 64 + col] = __float2half(fmaxf(ac[tt][r] + bias, 0.f));
            }
        }
    }
}

// fused layers 1/2. LAST=1 fuses layer-3 projection -> s3,r3.
template <int LAST>
__global__ __launch_bounds__(512) void fused_layer(
    const __half* __restrict__ xroot, const int* __restrict__ off, const int* __restrict__ end,
    const int* __restrict__ csr, const float* __restrict__ invd,
    const float* __restrict__ Wl, const float* __restrict__ bl, const float* __restrict__ Wr,
    __half* __restrict__ xnext,
    const float* __restrict__ Wl3, const float* __restrict__ bl3, const float* __restrict__ Wr3,
    float* __restrict__ s3, float* __restrict__ r3, int N) {
    __shared__ _Float16 act[64 * 136];
    __shared__ _Float16 wt[64 * 136];
    __shared__ float bs[64];
    int t = threadIdx.x;
    for (int i = t; i < 8192; i += 512) {
        int k = i >> 6, c = i & 63;
        float v = (k < 64) ? Wl[k * 64 + c] : Wr[(k - 64) * 64 + c];
        wt[c * 136 + k] = (_Float16)v;
    }
    if (t < 64) bs[t] = bl[t];
    int n0 = blockIdx.x * 64;
    {
        int node = t >> 3, cc8 = (t & 7) * 8;
        int n = min(n0 + node, N - 1);
        uint4 rv = *(const uint4*)(xroot + (size_t)n * 64 + cc8);
        *(uint4*)&act[node * 136 + 64 + cc8] = rv;
    }
    int lane = t & 63, wid = t >> 6;
    int g = lane >> 3, c8 = (lane & 7) * 8;
#pragma unroll 1
    for (int rr = 0; rr < 8; rr++) {
        int nloc = rr * 8 + wid;
        int n = min(n0 + nloc, N - 1);
        float sc = invd[n];
        int e0 = off[n], e1 = end[n];
        float acc[8] = {0, 0, 0, 0, 0, 0, 0, 0};
        int e = e0;
        for (; e + 31 < e1; e += 32) {
            int s0 = csr[e + g];
            int s1 = csr[e + 8 + g];
            int s2 = csr[e + 16 + g];
            int s3v = csr[e + 24 + g];
            uint4 h0 = *(const uint4*)(xroot + (size_t)s0 * 64 + c8);
            uint4 h1 = *(const uint4*)(xroot + (size_t)s1 * 64 + c8);
            uint4 h2 = *(const uint4*)(xroot + (size_t)s2 * 64 + c8);
            uint4 h3 = *(const uint4*)(xroot + (size_t)s3v * 64 + c8);
            acc8(acc, h0);
            acc8(acc, h1);
            acc8(acc, h2);
            acc8(acc, h3);
        }
        if (e + 15 < e1) {
            int s0 = csr[e + g];
            int s1 = csr[e + 8 + g];
            uint4 h0 = *(const uint4*)(xroot + (size_t)s0 * 64 + c8);
            uint4 h1 = *(const uint4*)(xroot + (size_t)s1 * 64 + c8);
            acc8(acc, h0);
            acc8(acc, h1);
            e += 16;
        }
        if (e + 7 < e1) {
            uint4 h0 = *(const uint4*)(xroot + (size_t)csr[e + g] * 64 + c8);
            acc8(acc, h0);
            e += 8;
        }
        if (e + g < e1) {
            uint4 h0 = *(const uint4*)(xroot + (size_t)csr[e + g] * 64 + c8);
            acc8(acc, h0);
        }
#pragma unroll
        for (int o = 8; o <= 32; o <<= 1) {
#pragma unroll
            for (int j = 0; j < 8; j++) acc[j] += __shfl_xor(acc[j], o);
        }
        if (lane < 8) {
            __half2 p[4];
#pragma unroll
            for (int j = 0; j < 4; j++)
                p[j] = __floats2half2_rn(acc[2 * j] * sc, acc[2 * j + 1] * sc);
            *(uint4*)&act[nloc * 136 + lane * 8] = *(const uint4*)p;
        }
    }
    __syncthreads();
    if (wid < 4) {
        int row = lane & 15, kg = lane >> 4;
        const _Float16* abase = &act[(wid * 16 + row) * 136 + kg * 8];
        half8 a[4];
#pragma unroll
        for (int kk = 0; kk < 4; kk++) a[kk] = *(const half8*)(abase + kk * 32);
        floatx4 ac[4];
#pragma unroll
        for (int tt = 0; tt < 4; tt++) ac[tt] = (floatx4){0.f, 0.f, 0.f, 0.f};
#pragma unroll
        for (int kk = 0; kk < 4; kk++) {
#pragma unroll
            for (int tt = 0; tt < 4; tt++) {
                half8 b = *(const half8*)&wt[(tt * 16 + row) * 136 + kk * 32 + kg * 8];
                ac[tt] = __builtin_amdgcn_mfma_f32_16x16x32_f16(a[kk], b, ac[tt], 0, 0, 0);
            }
        }
        if (LAST == 0) {
#pragma unroll
            for (int tt = 0; tt < 4; tt++) {
                int col = tt * 16 + row;
                float bias = bs[col];
#pragma unroll
                for (int r = 0; r < 4; r++) {
                    int n = n0 + wid * 16 + kg * 4 + r;
                    if (n < N)
                        xnext[(size_t)n * 64 + col] = __float2half(fmaxf(ac[tt][r] + bias, 0.f));
                }
            }
        } else {
            float wl3v[4], wr3v[4];
#pragma unroll
            for (int tt = 0; tt < 4; tt++) {
                int col = tt * 16 + row;
                wl3v[tt] = Wl3[col];
                wr3v[tt] = Wr3[col];
            }
            float b3 = bl3[0];
            float sp[4], rp[4];
#pragma unroll
            for (int r = 0; r < 4; r++) {
                float spv = 0.f, rpv = 0.f;
#pragma unroll
                for (int tt = 0; tt < 4; tt++) {
                    float v = fmaxf(ac[tt][r] + bs[tt * 16 + row], 0.f);
                    spv += v * wl3v[tt];
                    rpv += v * wr3v[tt];
                }
                sp[r] = spv;
                rp[r] = rpv;
            }
#pragma unroll
            for (int o = 1; o <= 8; o <<= 1) {
#pragma unroll
                for (int r = 0; r < 4; r++) {
                    sp[r] += __shfl_xor(sp[r], o);
                    rp[r] += __shfl_xor(rp[r], o);
                }
            }
            if (row == 0) {
#pragma unroll
                for (int r = 0; r < 4; r++) {
                    int n = n0 + wid * 16 + kg * 4 + r;
                    if (n < N) {
                        s3[n] = sp[r];
                        r3[n] = rp[r] + b3;
                    }
                }
            }
        }
    }
}

__global__ void sage_last_scalar(
    const float* __restrict__ s3, const float* __restrict__ r3, const int* __restrict__ off,
    const int* __restrict__ end, const int* __restrict__ csr, const float* __restrict__ invd,
    float* __restrict__ out, int N) {
    int n = blockIdx.x * blockDim.x + threadIdx.x;
    if (n >= N) return;
    int e0 = off[n], e1 = end[n];
    float acc = 0.f;
    int e = e0;
    for (; e + 3 < e1; e += 4) {
        float a0 = s3[csr[e]], a1 = s3[csr[e + 1]], a2 = s3[csr[e + 2]], a3 = s3[csr[e + 3]];
        acc += a0 + a1 + a2 + a3;
    }
    for (; e < e1; e++) acc += s3[csr[e]];
    out[n] = acc * invd[n] + r3[n];
}

// ---------------- launch ----------------

extern "C" void kernel_launch(void* const* d_in, const int* in_sizes, int n_in,
                              void* d_out, int out_size, void* d_ws, size_t ws_size,
                              hipStream_t stream) {
    const float* x0 = (const float*)d_in[0];
    const int* ei = (const int*)d_in[1];
    const float* Wl[4] = {(const float*)d_in[2], (const float*)d_in[5], (const float*)d_in[8],
                          (const float*)d_in[11]};
    const float* bl[4] = {(const float*)d_in[3], (const float*)d_in[6], (const float*)d_in[9],
                          (const float*)d_in[12]};
    const float* Wr[4] = {(const float*)d_in[4], (const float*)d_in[7], (const float*)d_in[10],
                          (const float*)d_in[13]};
    float* out = (float*)d_out;

    const int N = in_sizes[0] / 13;
    const int E = in_sizes[1] / 2;
    const int nbuk = (N + NPB - 1) / NPB;

    char* w = (char*)d_ws;
    auto carve = [&](size_t bytes) {
        void* p = (void*)w;
        w += (bytes + 255) & ~size_t(255);
        return p;
    };
    int* bcur = (int*)carve((size_t)MAXBUK * 4);
    unsigned int* pairs = (unsigned int*)carve((size_t)nbuk * CAP * 4);
    int* csr_off = (int*)carve((size_t)N * 4);
    int* csr_end = (int*)carve((size_t)N * 4);
    int* csr_src = (int*)carve((size_t)nbuk * CAP * 4);
    float* invd = (float*)carve((size_t)N * 4);
    __half* xroot0 = (__half*)carve((size_t)N * 16 * 2);
    __half* xroot1 = (__half*)carve((size_t)N * 64 * 2);
    __half* xroot2 = (__half*)carve((size_t)N * 64 * 2);
    float* s3 = (float*)carve((size_t)N * 4);
    float* r3 = (float*)carve((size_t)N * 4);

    init_bcur<<<(nbuk + 255) / 256, 256, 0, stream>>>(bcur, nbuk);
    partition<<<(E + A3_TILE - 1) / A3_TILE, 256, 0, stream>>>(ei, E, bcur, pairs);
    build_bucket<<<nbuk, 512, 0, stream>>>(pairs, bcur, csr_off, csr_end, csr_src, invd, N);

    pad_x<<<(N * 16 + NT - 1) / NT, NT, 0, stream>>>(x0, xroot0, N);

    int gblk = (N + 63) / 64;
    fused0<<<gblk, 512, 0, stream>>>(xroot0, csr_off, csr_end, csr_src, invd,
                                     Wl[0], bl[0], Wr[0], xroot1, N);
    fused_layer<0><<<gblk, 512, 0, stream>>>(xroot1, csr_off, csr_end, csr_src, invd,
                                             Wl[1], bl[1], Wr[1], xroot2,
                                             nullptr, nullptr, nullptr, nullptr, nullptr, N);
    fused_layer<1><<<gblk, 512, 0, stream>>>(xroot2, csr_off, csr_end, csr_src, invd,
                                             Wl[2], bl[2], Wr[2], nullptr,
                                             Wl[3], bl[3], Wr[3], s3, r3, N);
    sage_last_scalar<<<(N + NT - 1) / NT, NT, 0, stream>>>(s3, r3, csr_off, csr_end, csr_src,
                                                           invd, out, N);
}